// Round 1
// baseline (1080.250 us; speedup 1.0000x reference)
//
#include <hip/hip_runtime.h>
#include <math.h>

namespace {
constexpr int kB = 8;
constexpr int kC = 64;
constexpr int kH = 512;
constexpr int kW = 257;              // rfft half-width
constexpr int kN = kH * kW;          // 131584 pixels per batch
constexpr int kBands = 8;
constexpr int kGroups = kN / 4;      // 32896 float4 groups per batch
constexpr int kBlocksPerBatch = (kGroups + 255) / 256;  // 129
}

// Bit-exact replication of the reference band computation (all fp32 ops are
// exact or correctly rounded; see analysis): jx^2+jy^2 < 2^24 so the scaled
// sum is exact; sqrtf and '/' are IEEE correctly rounded by default on HIP.
__device__ __forceinline__ int band_of(int n) {
    int y = n / kW;
    int x = n - y * kW;
    int ky = (y < kH / 2) ? y : (kH - y);           // |fftfreq| numerator
    float rsq = (float)(x * x + ky * ky) * (1.0f / 262144.0f);  // /512^2, exact
    float r = sqrtf(rsq) / sqrtf(0.5f);             // == radius / radius.max()
    int band = 0;                                    // searchsorted(side='left'):
    band += (r > 0.125f);                            // count of edges strictly < r
    band += (r > 0.25f);
    band += (r > 0.375f);
    band += (r > 0.5f);
    band += (r > 0.625f);
    band += (r > 0.75f);
    band += (r > 0.875f);
    return band;
}

// Kernel 1: per-pixel log1p-magnitude means over channels, accumulated into
// per-(batch,band) {low_sum, high_sum, low_sumsq, high_sumsq} + band counts.
__global__ __launch_bounds__(256)
void RadialBandGate_stats(const float* __restrict__ lre, const float* __restrict__ lim,
                          const float* __restrict__ hre, const float* __restrict__ him,
                          float* __restrict__ stats /* [B][bands][4] */,
                          float* __restrict__ counts /* [bands] */) {
    const int b = blockIdx.y;
    const int g = blockIdx.x * 256 + threadIdx.x;

    __shared__ float s_acc[kBands][4];
    __shared__ float s_cnt[kBands];
    if (threadIdx.x < kBands) {
        s_acc[threadIdx.x][0] = 0.0f;
        s_acc[threadIdx.x][1] = 0.0f;
        s_acc[threadIdx.x][2] = 0.0f;
        s_acc[threadIdx.x][3] = 0.0f;
        s_cnt[threadIdx.x] = 0.0f;
    }
    __syncthreads();

    if (g < kGroups) {
        const float4* lre4 = reinterpret_cast<const float4*>(lre);
        const float4* lim4 = reinterpret_cast<const float4*>(lim);
        const float4* hre4 = reinterpret_cast<const float4*>(hre);
        const float4* him4 = reinterpret_cast<const float4*>(him);
        const size_t base = (size_t)b * kC * kGroups + g;

        float ls0 = 0.f, ls1 = 0.f, ls2 = 0.f, ls3 = 0.f;
        float hs0 = 0.f, hs1 = 0.f, hs2 = 0.f, hs3 = 0.f;
#pragma unroll 4
        for (int c = 0; c < kC; ++c) {
            const size_t idx = base + (size_t)c * kGroups;
            float4 ar = lre4[idx];
            float4 ai = lim4[idx];
            float4 br = hre4[idx];
            float4 bi = him4[idx];
            ls0 += log1pf(sqrtf(ar.x * ar.x + ai.x * ai.x));
            ls1 += log1pf(sqrtf(ar.y * ar.y + ai.y * ai.y));
            ls2 += log1pf(sqrtf(ar.z * ar.z + ai.z * ai.z));
            ls3 += log1pf(sqrtf(ar.w * ar.w + ai.w * ai.w));
            hs0 += log1pf(sqrtf(br.x * br.x + bi.x * bi.x));
            hs1 += log1pf(sqrtf(br.y * br.y + bi.y * bi.y));
            hs2 += log1pf(sqrtf(br.z * br.z + bi.z * bi.z));
            hs3 += log1pf(sqrtf(br.w * br.w + bi.w * bi.w));
        }

        const float inv = 1.0f / 64.0f;
        float xl[4] = {ls0 * inv, ls1 * inv, ls2 * inv, ls3 * inv};
        float xh[4] = {hs0 * inv, hs1 * inv, hs2 * inv, hs3 * inv};
        const int n0 = g * 4;
#pragma unroll
        for (int p = 0; p < 4; ++p) {
            const int band = band_of(n0 + p);
            atomicAdd(&s_acc[band][0], xl[p]);
            atomicAdd(&s_acc[band][1], xh[p]);
            atomicAdd(&s_acc[band][2], xl[p] * xl[p]);
            atomicAdd(&s_acc[band][3], xh[p] * xh[p]);
            if (b == 0) atomicAdd(&s_cnt[band], 1.0f);  // counts are batch-independent
        }
    }
    __syncthreads();

    if (threadIdx.x < kBands * 4) {
        const int band = threadIdx.x >> 2;
        const int j = threadIdx.x & 3;
        atomicAdd(&stats[((size_t)b * kBands + band) * 4 + j], s_acc[band][j]);
    }
    if (b == 0 && threadIdx.x < kBands) {
        atomicAdd(&counts[threadIdx.x], s_cnt[threadIdx.x]);
    }
}

// Kernel 2: band stats -> feats -> erf-GELU MLP -> sigmoid. 64 rows, 1 wave.
__global__ __launch_bounds__(64)
void RadialBandGate_mlp(const float* __restrict__ stats, const float* __restrict__ counts,
                        const float* __restrict__ W1, const float* __restrict__ b1,
                        const float* __restrict__ W2, const float* __restrict__ b2,
                        const float* __restrict__ band_bias, float* __restrict__ alpha) {
    const int t = threadIdx.x;
    if (t >= kB * kBands) return;
    const int j = t & (kBands - 1);
    const float cnt = fmaxf(counts[j], 1.0f);   // clamp_min(1.0); counts>=1 anyway
    const float* s = stats + t * 4;
    const float lsum = s[0], hsum = s[1], lsq = s[2], hsq = s[3];

    const float lm = lsum / cnt;
    const float hm = hsum / cnt;
    // Var = (Sum x^2 - (Sum x)^2 / n) / n, in double to avoid cancellation.
    const double dc = (double)cnt;
    const double lvar = ((double)lsq - (double)lsum * (double)lsum / dc) / dc;
    const double hvar = ((double)hsq - (double)hsum * (double)hsum / dc) / dc;
    const float lstd = sqrtf((float)fmax(lvar, 0.0));
    const float hstd = sqrtf((float)fmax(hvar, 0.0));

    // feats = [low_mean, high_mean, low_std, high_std]; all finite -> no nan_to_num
    const float f0 = lm, f1 = hm, f2 = lstd, f3 = hstd;

    float logit = b2[0] + band_bias[j];
#pragma unroll
    for (int k = 0; k < 32; ++k) {
        float pre = b1[k] + f0 * W1[k * 4 + 0] + f1 * W1[k * 4 + 1] +
                    f2 * W1[k * 4 + 2] + f3 * W1[k * 4 + 3];
        float ge = 0.5f * pre * (1.0f + erff(pre * 0.70710678f));  // exact GELU
        logit += ge * W2[k];
    }
    alpha[t] = 1.0f / (1.0f + expf(-logit));
}

// Kernel 3: broadcast per-(batch,band) alpha to the (B,1,H,Wr) map.
__global__ __launch_bounds__(256)
void RadialBandGate_gate(const float* __restrict__ alpha, float* __restrict__ out) {
    __shared__ float s_a[kBands];
    const int b = blockIdx.y;
    if (threadIdx.x < kBands) s_a[threadIdx.x] = alpha[b * kBands + threadIdx.x];
    __syncthreads();
    const int n = blockIdx.x * 256 + threadIdx.x;   // kN == 514*256 exactly
    out[(size_t)b * kN + n] = s_a[band_of(n)];
}

extern "C" void kernel_launch(void* const* d_in, const int* in_sizes, int n_in,
                              void* d_out, int out_size, void* d_ws, size_t ws_size,
                              hipStream_t stream) {
    const float* lre = (const float*)d_in[0];
    const float* lim = (const float*)d_in[1];
    const float* hre = (const float*)d_in[2];
    const float* him = (const float*)d_in[3];
    const float* W1 = (const float*)d_in[4];
    const float* b1 = (const float*)d_in[5];
    const float* W2 = (const float*)d_in[6];
    const float* b2 = (const float*)d_in[7];
    const float* bb = (const float*)d_in[8];

    float* stats = (float*)d_ws;                  // kB*kBands*4 = 256 floats
    float* counts = stats + kB * kBands * 4;      // 8 floats
    float* alpha = counts + kBands;               // 64 floats

    // ws is re-poisoned to 0xAA before every timed launch; zero the accumulators.
    hipMemsetAsync(d_ws, 0, (kB * kBands * 4 + kBands) * sizeof(float), stream);

    RadialBandGate_stats<<<dim3(kBlocksPerBatch, kB), 256, 0, stream>>>(
        lre, lim, hre, him, stats, counts);
    RadialBandGate_mlp<<<1, 64, 0, stream>>>(stats, counts, W1, b1, W2, b2, bb, alpha);
    RadialBandGate_gate<<<dim3(kN / 256, kB), 256, 0, stream>>>(alpha, (float*)d_out);
}

// Round 2
// 826.698 us; speedup vs baseline: 1.3067x; 1.3067x over previous
//
#include <hip/hip_runtime.h>
#include <math.h>

namespace {
constexpr int kB = 8;
constexpr int kC = 64;
constexpr int kH = 512;
constexpr int kW = 257;              // rfft half-width
constexpr int kN = kH * kW;          // 131584 pixels per batch
constexpr int kBands = 8;
constexpr int kGroups2 = kN / 2;     // 65792 float2 groups per batch
constexpr int kBlocksPerBatch = kGroups2 / 256;  // 257 exactly
constexpr float kLn2 = 0.69314718055994530942f;
}

// Exact integer band assignment, bit-equivalent to the reference fp32 chain:
// r > k/8  <=>  (x^2+ky^2)/2^17 > k^2/64  <=>  x^2+ky^2 > 2048*k^2.
// (Nearest off-edge lattice point is >=5e-6 relative from an edge; the fp32
// chain's error is ~1.2e-7 relative, so the comparisons can never disagree.
// Exact-edge pixels: strict '>' on both sides -> lower band, matching
// searchsorted side='left'.)
__device__ __forceinline__ int band_of(int n) {
    int y = n / kW;                       // compiler strength-reduces (magic mul)
    int x = n - y * kW;
    int ky = (y < kH / 2) ? y : (kH - y); // |fftfreq| numerator
    int s = x * x + ky * ky;
    return (s > 2048) + (s > 8192) + (s > 18432) + (s > 32768) +
           (s > 51200) + (s > 73728) + (s > 100352);
}

// log1p(sqrt(v)) in log2 domain via HW v_sqrt_f32 / v_log_f32 (~1 ulp each);
// caller multiplies the channel-sum by ln2/64 once.
__device__ __forceinline__ float log2_mag(float re, float im) {
    float v = __builtin_amdgcn_sqrtf(fmaf(re, re, im * im));
    return __builtin_amdgcn_logf(1.0f + v);
}

// Kernel 1: per-pixel log1p-magnitude means over channels, accumulated into
// per-(batch,band) {low_sum, high_sum, low_sumsq, high_sumsq} + band counts.
__global__ __launch_bounds__(256, 4)
void RadialBandGate_stats(const float* __restrict__ lre, const float* __restrict__ lim,
                          const float* __restrict__ hre, const float* __restrict__ him,
                          float* __restrict__ stats /* [B][bands][4] */,
                          float* __restrict__ counts /* [bands] */) {
    const int b = blockIdx.y;
    const int g = blockIdx.x * 256 + threadIdx.x;   // float2 group, always in range

    __shared__ float s_acc[kBands][4];
    __shared__ float s_cnt[kBands];
    if (threadIdx.x < kBands) {
        s_acc[threadIdx.x][0] = 0.0f;
        s_acc[threadIdx.x][1] = 0.0f;
        s_acc[threadIdx.x][2] = 0.0f;
        s_acc[threadIdx.x][3] = 0.0f;
        s_cnt[threadIdx.x] = 0.0f;
    }
    __syncthreads();

    const float2* lre2 = reinterpret_cast<const float2*>(lre);
    const float2* lim2 = reinterpret_cast<const float2*>(lim);
    const float2* hre2 = reinterpret_cast<const float2*>(hre);
    const float2* him2 = reinterpret_cast<const float2*>(him);
    const size_t base = (size_t)b * kC * kGroups2 + g;

    float ls0 = 0.f, ls1 = 0.f, hs0 = 0.f, hs1 = 0.f;   // log2-domain sums
#pragma unroll 4
    for (int c = 0; c < kC; ++c) {
        const size_t idx = base + (size_t)c * kGroups2;
        float2 ar = lre2[idx];
        float2 ai = lim2[idx];
        float2 br = hre2[idx];
        float2 bi = him2[idx];
        ls0 += log2_mag(ar.x, ai.x);
        ls1 += log2_mag(ar.y, ai.y);
        hs0 += log2_mag(br.x, bi.x);
        hs1 += log2_mag(br.y, bi.y);
    }

    const float scale = kLn2 / 64.0f;
    float xl[2] = {ls0 * scale, ls1 * scale};
    float xh[2] = {hs0 * scale, hs1 * scale};
    const int n0 = g * 2;
#pragma unroll
    for (int p = 0; p < 2; ++p) {
        const int band = band_of(n0 + p);
        atomicAdd(&s_acc[band][0], xl[p]);
        atomicAdd(&s_acc[band][1], xh[p]);
        atomicAdd(&s_acc[band][2], xl[p] * xl[p]);
        atomicAdd(&s_acc[band][3], xh[p] * xh[p]);
        if (b == 0) atomicAdd(&s_cnt[band], 1.0f);  // counts are batch-independent
    }
    __syncthreads();

    if (threadIdx.x < kBands * 4) {
        const int band = threadIdx.x >> 2;
        const int j = threadIdx.x & 3;
        atomicAdd(&stats[((size_t)b * kBands + band) * 4 + j], s_acc[band][j]);
    }
    if (b == 0 && threadIdx.x < kBands) {
        atomicAdd(&counts[threadIdx.x], s_cnt[threadIdx.x]);
    }
}

// Kernel 2: band stats -> feats -> erf-GELU MLP -> sigmoid. 64 rows, 1 wave.
__global__ __launch_bounds__(64)
void RadialBandGate_mlp(const float* __restrict__ stats, const float* __restrict__ counts,
                        const float* __restrict__ W1, const float* __restrict__ b1,
                        const float* __restrict__ W2, const float* __restrict__ b2,
                        const float* __restrict__ band_bias, float* __restrict__ alpha) {
    const int t = threadIdx.x;
    if (t >= kB * kBands) return;
    const int j = t & (kBands - 1);
    const float cnt = fmaxf(counts[j], 1.0f);
    const float* s = stats + t * 4;
    const float lsum = s[0], hsum = s[1], lsq = s[2], hsq = s[3];

    const float lm = lsum / cnt;
    const float hm = hsum / cnt;
    // Var = (Sum x^2 - (Sum x)^2 / n) / n, in double to avoid cancellation.
    const double dc = (double)cnt;
    const double lvar = ((double)lsq - (double)lsum * (double)lsum / dc) / dc;
    const double hvar = ((double)hsq - (double)hsum * (double)hsum / dc) / dc;
    const float lstd = sqrtf((float)fmax(lvar, 0.0));
    const float hstd = sqrtf((float)fmax(hvar, 0.0));

    const float f0 = lm, f1 = hm, f2 = lstd, f3 = hstd;

    float logit = b2[0] + band_bias[j];
#pragma unroll
    for (int k = 0; k < 32; ++k) {
        float pre = b1[k] + f0 * W1[k * 4 + 0] + f1 * W1[k * 4 + 1] +
                    f2 * W1[k * 4 + 2] + f3 * W1[k * 4 + 3];
        float ge = 0.5f * pre * (1.0f + erff(pre * 0.70710678f));  // exact GELU
        logit += ge * W2[k];
    }
    alpha[t] = 1.0f / (1.0f + expf(-logit));
}

// Kernel 3: broadcast per-(batch,band) alpha to the (B,1,H,Wr) map.
__global__ __launch_bounds__(256)
void RadialBandGate_gate(const float* __restrict__ alpha, float* __restrict__ out) {
    __shared__ float s_a[kBands];
    const int b = blockIdx.y;
    if (threadIdx.x < kBands) s_a[threadIdx.x] = alpha[b * kBands + threadIdx.x];
    __syncthreads();
    const int n = blockIdx.x * 256 + threadIdx.x;   // kN == 514*256 exactly
    out[(size_t)b * kN + n] = s_a[band_of(n)];
}

extern "C" void kernel_launch(void* const* d_in, const int* in_sizes, int n_in,
                              void* d_out, int out_size, void* d_ws, size_t ws_size,
                              hipStream_t stream) {
    const float* lre = (const float*)d_in[0];
    const float* lim = (const float*)d_in[1];
    const float* hre = (const float*)d_in[2];
    const float* him = (const float*)d_in[3];
    const float* W1 = (const float*)d_in[4];
    const float* b1 = (const float*)d_in[5];
    const float* W2 = (const float*)d_in[6];
    const float* b2 = (const float*)d_in[7];
    const float* bb = (const float*)d_in[8];

    float* stats = (float*)d_ws;                  // kB*kBands*4 = 256 floats
    float* counts = stats + kB * kBands * 4;      // 8 floats
    float* alpha = counts + kBands;               // 64 floats

    hipMemsetAsync(d_ws, 0, (kB * kBands * 4 + kBands) * sizeof(float), stream);

    RadialBandGate_stats<<<dim3(kBlocksPerBatch, kB), 256, 0, stream>>>(
        lre, lim, hre, him, stats, counts);
    RadialBandGate_mlp<<<1, 64, 0, stream>>>(stats, counts, W1, b1, W2, b2, bb, alpha);
    RadialBandGate_gate<<<dim3(kN / 256, kB), 256, 0, stream>>>(alpha, (float*)d_out);
}